// Round 5
// baseline (71.166 us; speedup 1.0000x reference)
//
#include <hip/hip_runtime.h>

#define MU_F    0.02f
#define MU2_F   4.0e-4f
// slow-path gate on d2 = d*d + mu2.  True bin-29 boundary: d2 >= mu2*900/59
// = 6.10169e-3.  Use 6.2e-3 (conservative margin): everything below takes the
// exact-bin slow path; fast path is provably bin 29 under fp32 rounding.
#define TSLOW_F 6.2e-3f
#define BINS    30
#define ROWS    62                 // 0..29 R_b(slow), 30..59 C_b, 60 RA, 61 CA
#define THREADS 256
#define NBLK    2048

// ---------------------------------------------------------------------------
// Per-element: fast path (bin 29, ~95.7%) accumulates raw r = sqrt(d2) and an
// int count in registers (loss = r - mu is folded into the finalize).
// Slow path (d2 < TSLOW): LDS atomics with the exact bin (idx==29 strays are
// added back in the finalize).
// ---------------------------------------------------------------------------
__device__ __forceinline__ void ghmr_elem(float pj, float tj, float wj,
                                          float& sumR, int& cntV,
                                          float* s_sum, unsigned int* s_cnt)
{
    float d  = pj - tj;
    float d2 = fmaf(d, d, MU2_F);
    float r  = __builtin_amdgcn_sqrtf(d2);   // raw v_sqrt_f32, ~1ulp
    bool valid = wj > 0.0f;
    sumR += valid ? r : 0.0f;
    cntV += valid ? 1 : 0;
    if (valid && d2 < TSLOW_F) {
        float g   = fabsf(d) * __builtin_amdgcn_rsqf(d2);
        int   idx = (int)(g * 30.0f);
        idx = idx > BINS - 1 ? BINS - 1 : idx;
        atomicAdd(&s_sum[idx], r);
        atomicAdd(&s_cnt[idx], 1u);
    }
}

struct Chunk {
    float4 p0, p1, p2, p3;
    float4 t0, t1, t2, t3;
    float4 w0, w1, w2, w3;
};

__device__ __forceinline__ void load_chunk(Chunk& c,
    const float4* __restrict__ pred, const float4* __restrict__ target,
    const float4* __restrict__ lw, int g)
{
    const int b = 4 * g;
    c.p0 = pred[b+0]; c.p1 = pred[b+1]; c.p2 = pred[b+2]; c.p3 = pred[b+3];
    c.t0 = target[b+0]; c.t1 = target[b+1]; c.t2 = target[b+2]; c.t3 = target[b+3];
    c.w0 = lw[b+0]; c.w1 = lw[b+1]; c.w2 = lw[b+2]; c.w3 = lw[b+3];
}

#define GHMR_PROC(P,TT,W) do { \
    ghmr_elem((P).x,(TT).x,(W).x,sumR,cntV,s_sum,s_cnt); \
    ghmr_elem((P).y,(TT).y,(W).y,sumR,cntV,s_sum,s_cnt); \
    ghmr_elem((P).z,(TT).z,(W).z,sumR,cntV,s_sum,s_cnt); \
    ghmr_elem((P).w,(TT).w,(W).w,sumR,cntV,s_sum,s_cnt); } while(0)

__device__ __forceinline__ void proc_chunk(const Chunk& c,
    float& sumR, int& cntV, float* s_sum, unsigned int* s_cnt)
{
    GHMR_PROC(c.p0, c.t0, c.w0);
    GHMR_PROC(c.p1, c.t1, c.w1);
    GHMR_PROC(c.p2, c.t2, c.w2);
    GHMR_PROC(c.p3, c.t3, c.w3);
}

#define GHMR_TAIL() do { \
    for (int off = 32; off > 0; off >>= 1) { \
        sumR += __shfl_down(sumR, off); \
        cntV += __shfl_down(cntV, off); \
    } \
    if ((tid & 63) == 0) { atomicAdd(&s_allR, sumR); atomicAdd(&s_allC, (unsigned)cntV); } \
    __syncthreads(); \
    const int bid = blockIdx.x; \
    if (tid < BINS)            part[tid*pstride + bid] = s_sum[tid]; \
    else if (tid < 2*BINS)     part[tid*pstride + bid] = (float)s_cnt[tid-BINS]; \
    else if (tid == 2*BINS)    part[60*pstride + bid] = s_allR; \
    else if (tid == 2*BINS+1)  part[61*pstride + bid] = (float)s_allC; } while(0)

// ---------------------------------------------------------------------------
// Chunked hist with register double-buffer: next chunk's 12 loads are issued
// before processing the current chunk (sched_barrier pins the order), so 12KB
// per wave stays in flight under the compute phase.
// ---------------------------------------------------------------------------
__global__ __launch_bounds__(THREADS, 4) void ghmr_hist_chunk(
    const float4* __restrict__ pred, const float4* __restrict__ target,
    const float4* __restrict__ lw, float* __restrict__ part,
    int pstride, int nchunks)
{
    __shared__ float        s_sum[BINS];
    __shared__ unsigned int s_cnt[BINS];
    __shared__ float        s_allR;
    __shared__ unsigned int s_allC;

    const int tid = threadIdx.x;
    if (tid < BINS) { s_sum[tid] = 0.0f; s_cnt[tid] = 0u; }
    if (tid == 0)   { s_allR = 0.0f; s_allC = 0u; }
    __syncthreads();

    float sumR = 0.0f;
    int   cntV = 0;

    const int G = gridDim.x * THREADS;
    int g = blockIdx.x * THREADS + tid;

    if (g < nchunks) {
        Chunk A, B;
        load_chunk(A, pred, target, lw, g);
        g += G;
        bool pendA = true;                    // wave-uniform
        while (g < nchunks) {
            if (pendA) {
                load_chunk(B, pred, target, lw, g);
                __builtin_amdgcn_sched_barrier(0);
                proc_chunk(A, sumR, cntV, s_sum, s_cnt);
            } else {
                load_chunk(A, pred, target, lw, g);
                __builtin_amdgcn_sched_barrier(0);
                proc_chunk(B, sumR, cntV, s_sum, s_cnt);
            }
            pendA = !pendA;
            g += G;
        }
        if (pendA) proc_chunk(A, sumR, cntV, s_sum, s_cnt);
        else       proc_chunk(B, sumR, cntV, s_sum, s_cnt);
    }

    GHMR_TAIL();
}

// ---------------------------------------------------------------------------
// Generic fallback (any n): grid-stride float4 + scalar tail.
// ---------------------------------------------------------------------------
__global__ __launch_bounds__(THREADS) void ghmr_hist_gen(
    const float* __restrict__ predf, const float* __restrict__ targetf,
    const float* __restrict__ lwf, float* __restrict__ part,
    int pstride, int n)
{
    __shared__ float        s_sum[BINS];
    __shared__ unsigned int s_cnt[BINS];
    __shared__ float        s_allR;
    __shared__ unsigned int s_allC;

    const int tid = threadIdx.x;
    if (tid < BINS) { s_sum[tid] = 0.0f; s_cnt[tid] = 0u; }
    if (tid == 0)   { s_allR = 0.0f; s_allC = 0u; }
    __syncthreads();

    float sumR = 0.0f;
    int   cntV = 0;

    const int n4 = n / 4;
    const float4* pred   = (const float4*)predf;
    const float4* target = (const float4*)targetf;
    const float4* lw     = (const float4*)lwf;

    for (int i = blockIdx.x*THREADS + tid; i < n4; i += gridDim.x*THREADS) {
        float4 p = pred[i], t = target[i], w = lw[i];
        GHMR_PROC(p,t,w);
    }
    int rem = n - n4*4;
    if (blockIdx.x == 0 && tid < rem) {
        int i = n4*4 + tid;
        ghmr_elem(predf[i], targetf[i], lwf[i], sumR, cntV, s_sum, s_cnt);
    }

    GHMR_TAIL();
}

// ---------------------------------------------------------------------------
// Reduce stage 1: 62 blocks, one transposed row each; coalesced.
// ---------------------------------------------------------------------------
__global__ __launch_bounds__(256) void ghmr_reduce(
    const float* __restrict__ part, float* __restrict__ red,
    int pstride, int nblk)
{
    const int r = blockIdx.x;          // 0..ROWS-1
    float s = 0.0f;
    for (int i = threadIdx.x; i < nblk; i += 256)
        s += part[r*pstride + i];
    __shared__ float ls[4];
    for (int off = 32; off > 0; off >>= 1) s += __shfl_down(s, off);
    if ((threadIdx.x & 63) == 0) ls[threadIdx.x >> 6] = s;
    __syncthreads();
    if (threadIdx.x == 0) red[r] = ls[0] + ls[1] + ls[2] + ls[3];
}

// ---------------------------------------------------------------------------
// Finalize:  S_b = R_b - mu*C_b;  result = (1/n_nonempty) * sum_b S_b/max(C_b,1)
// bin29 reconstructed: R29 = (RA - sum_slow_R) + strays_R, same for C29.
// ---------------------------------------------------------------------------
__global__ void ghmr_final(const float* __restrict__ red, float* __restrict__ out)
{
    int b = threadIdx.x;   // 0..63
    float Rb = (b < BINS) ? red[b]        : 0.0f;
    float Cb = (b < BINS) ? red[BINS + b] : 0.0f;
    float RS = Rb, CS = Cb;
    for (int off = 1; off < 64; off <<= 1) { RS += __shfl_xor(RS, off); CS += __shfl_xor(CS, off); }
    float RA = red[60], CA = red[61];
    if (b == BINS - 1) { Rb = (RA - RS) + Rb; Cb = (CA - CS) + Cb; }
    float term = (b < BINS) ? (Rb - MU_F * Cb) / fmaxf(Cb, 1.0f) : 0.0f;
    float nz   = (b < BINS && Cb > 0.0f) ? 1.0f : 0.0f;
    for (int off = 1; off < 64; off <<= 1) { term += __shfl_xor(term, off); nz += __shfl_xor(nz, off); }
    if (b == 0) out[0] = term / fmaxf(nz, 1.0f);
}

// ---------------------------------------------------------------------------
extern "C" void kernel_launch(void* const* d_in, const int* in_sizes, int n_in,
                              void* d_out, int out_size, void* d_ws, size_t ws_size,
                              hipStream_t stream) {
    int n = in_sizes[0];

    int NB = NBLK;
    size_t need = (size_t)ROWS * (size_t)NB * sizeof(float) + ROWS * sizeof(float);
    bool ws_ok = need <= ws_size;
    if (!ws_ok) {
        NB = (int)((ws_size / sizeof(float) - ROWS) / ROWS);
        if (NB > NBLK) NB = NBLK;
        if (NB < 1) NB = 1;
    }
    int pstride = NB;
    float* part = (float*)d_ws;                  // [ROWS][pstride]
    float* red  = part + (size_t)ROWS * pstride; // [ROWS]

    bool fast = ws_ok && (n % 16 == 0) && n > 0;

    if (fast) {
        int nchunks = n / 16;
        ghmr_hist_chunk<<<NB, THREADS, 0, stream>>>(
            (const float4*)d_in[0], (const float4*)d_in[1], (const float4*)d_in[2],
            part, pstride, nchunks);
    } else {
        ghmr_hist_gen<<<NB, THREADS, 0, stream>>>(
            (const float*)d_in[0], (const float*)d_in[1], (const float*)d_in[2],
            part, pstride, n);
    }
    ghmr_reduce<<<ROWS, 256, 0, stream>>>(part, red, pstride, NB);
    ghmr_final<<<1, 64, 0, stream>>>(red, (float*)d_out);
}

// Round 6
// 41.357 us; speedup vs baseline: 1.7208x; 1.7208x over previous
//
#include <hip/hip_runtime.h>

#define MU_F    0.02f
#define MU2_F   4.0e-4f
// slow-path gate on d2 = d*d + mu2.  True bin-29 boundary: d2 >= mu2*900/59
// = 6.10169e-3.  Use 6.2e-3 (conservative margin): everything below takes the
// exact-bin slow path; fast path is provably bin 29 under fp32 rounding.
#define TSLOW_F 6.2e-3f
#define BINS    30
#define ROWS    62                 // 0..29 R_b(slow), 30..59 C_b, 60 RA, 61 CA
#define THREADS 256
#define NBLK    2048

// ---------------------------------------------------------------------------
// Per-element: fast path (~95.7%) accumulates raw r = v_sqrt_f32(d2) in a
// register; valid-count goes through ballot+popcount (scalar pipe, wave-
// uniform). Slow path (d2 < TSLOW): LDS atomics with the exact bin index
// (idx==29 strays are added back in the finalize).
// loss = r - mu is folded into the finalize: S_b = R_b - mu*C_b.
// ---------------------------------------------------------------------------
__device__ __forceinline__ void ghmr_elem(float pj, float tj, float wj,
                                          float& sumR, int& cntW,
                                          float* s_sum, unsigned int* s_cnt)
{
    float d  = pj - tj;
    float d2 = fmaf(d, d, MU2_F);
    float r  = __builtin_amdgcn_sqrtf(d2);   // raw v_sqrt_f32, ~1ulp
    bool valid = wj > 0.0f;
    sumR += valid ? r : 0.0f;
    // wave-total valid count on the scalar pipe; same value in every lane
    cntW += (int)__popcll(__ballot(valid));
    if (valid && d2 < TSLOW_F) {
        float g   = fabsf(d) * __builtin_amdgcn_rsqf(d2);
        int   idx = (int)(g * 30.0f);
        idx = idx > BINS - 1 ? BINS - 1 : idx;
        atomicAdd(&s_sum[idx], r);
        atomicAdd(&s_cnt[idx], 1u);
    }
}

#define GHMR_PROC(P,TT,W) do { \
    ghmr_elem((P).x,(TT).x,(W).x,sumR,cntW,s_sum,s_cnt); \
    ghmr_elem((P).y,(TT).y,(W).y,sumR,cntW,s_sum,s_cnt); \
    ghmr_elem((P).z,(TT).z,(W).z,sumR,cntW,s_sum,s_cnt); \
    ghmr_elem((P).w,(TT).w,(W).w,sumR,cntW,s_sum,s_cnt); } while(0)

// cntW is wave-uniform (lane 0 of each wave has the smallest index, hence is
// active whenever any lane is, so its accumulated ballot-count is the wave
// total). Only sumR needs the shuffle reduction.
#define GHMR_TAIL() do { \
    for (int off = 32; off > 0; off >>= 1) \
        sumR += __shfl_down(sumR, off); \
    if ((tid & 63) == 0) { atomicAdd(&s_allR, sumR); atomicAdd(&s_allC, (unsigned)cntW); } \
    __syncthreads(); \
    const int bid = blockIdx.x; \
    if (tid < BINS)            part[tid*pstride + bid] = s_sum[tid]; \
    else if (tid < 2*BINS)     part[tid*pstride + bid] = (float)s_cnt[tid-BINS]; \
    else if (tid == 2*BINS)    part[60*pstride + bid] = s_allR; \
    else if (tid == 2*BINS+1)  part[61*pstride + bid] = (float)s_allC; } while(0)

// ---------------------------------------------------------------------------
// Chunked hist (R3 structure, unchanged): each thread owns 4 consecutive
// float4s (64B) per stream per iteration; one wave instruction spans 4KB
// contiguous per stream; 12 loads issued before compute (sched_barrier).
// Requires n % 16 == 0; nchunks = n/16.
// ---------------------------------------------------------------------------
__global__ __launch_bounds__(THREADS, 4) void ghmr_hist_chunk(
    const float4* __restrict__ pred, const float4* __restrict__ target,
    const float4* __restrict__ lw, float* __restrict__ part,
    int pstride, int nchunks)
{
    __shared__ float        s_sum[BINS];
    __shared__ unsigned int s_cnt[BINS];
    __shared__ float        s_allR;
    __shared__ unsigned int s_allC;

    const int tid = threadIdx.x;
    if (tid < BINS) { s_sum[tid] = 0.0f; s_cnt[tid] = 0u; }
    if (tid == 0)   { s_allR = 0.0f; s_allC = 0u; }
    __syncthreads();

    float sumR = 0.0f;
    int   cntW = 0;

    const int G = gridDim.x * THREADS;
    for (int g = blockIdx.x * THREADS + tid; g < nchunks; g += G) {
        const int b = 4 * g;
        float4 p0 = pred[b+0], p1 = pred[b+1], p2 = pred[b+2], p3 = pred[b+3];
        float4 t0 = target[b+0], t1 = target[b+1], t2 = target[b+2], t3 = target[b+3];
        float4 w0 = lw[b+0], w1 = lw[b+1], w2 = lw[b+2], w3 = lw[b+3];
        __builtin_amdgcn_sched_barrier(0);   // issue all 12 loads before compute
        GHMR_PROC(p0,t0,w0);
        GHMR_PROC(p1,t1,w1);
        GHMR_PROC(p2,t2,w2);
        GHMR_PROC(p3,t3,w3);
    }

    GHMR_TAIL();
}

// ---------------------------------------------------------------------------
// Generic fallback (any n): grid-stride float4 + scalar tail.
// ---------------------------------------------------------------------------
__global__ __launch_bounds__(THREADS) void ghmr_hist_gen(
    const float* __restrict__ predf, const float* __restrict__ targetf,
    const float* __restrict__ lwf, float* __restrict__ part,
    int pstride, int n)
{
    __shared__ float        s_sum[BINS];
    __shared__ unsigned int s_cnt[BINS];
    __shared__ float        s_allR;
    __shared__ unsigned int s_allC;

    const int tid = threadIdx.x;
    if (tid < BINS) { s_sum[tid] = 0.0f; s_cnt[tid] = 0u; }
    if (tid == 0)   { s_allR = 0.0f; s_allC = 0u; }
    __syncthreads();

    float sumR = 0.0f;
    int   cntW = 0;

    const int n4 = n / 4;
    const float4* pred   = (const float4*)predf;
    const float4* target = (const float4*)targetf;
    const float4* lw     = (const float4*)lwf;

    for (int i = blockIdx.x*THREADS + tid; i < n4; i += gridDim.x*THREADS) {
        float4 p = pred[i], t = target[i], w = lw[i];
        GHMR_PROC(p,t,w);
    }
    int rem = n - n4*4;
    if (blockIdx.x == 0 && tid < rem) {
        int i = n4*4 + tid;
        ghmr_elem(predf[i], targetf[i], lwf[i], sumR, cntW, s_sum, s_cnt);
    }

    GHMR_TAIL();
}

// ---------------------------------------------------------------------------
// Reduce stage 1: 62 blocks, one transposed row each; coalesced.
// ---------------------------------------------------------------------------
__global__ __launch_bounds__(256) void ghmr_reduce(
    const float* __restrict__ part, float* __restrict__ red,
    int pstride, int nblk)
{
    const int r = blockIdx.x;          // 0..ROWS-1
    float s = 0.0f;
    for (int i = threadIdx.x; i < nblk; i += 256)
        s += part[r*pstride + i];
    __shared__ float ls[4];
    for (int off = 32; off > 0; off >>= 1) s += __shfl_down(s, off);
    if ((threadIdx.x & 63) == 0) ls[threadIdx.x >> 6] = s;
    __syncthreads();
    if (threadIdx.x == 0) red[r] = ls[0] + ls[1] + ls[2] + ls[3];
}

// ---------------------------------------------------------------------------
// Finalize:  S_b = R_b - mu*C_b;  result = (1/n_nonempty) * sum_b S_b/max(C_b,1)
// bin29 reconstructed: R29 = (RA - sum_slow_R) + strays_R, same for C29.
// ---------------------------------------------------------------------------
__global__ void ghmr_final(const float* __restrict__ red, float* __restrict__ out)
{
    int b = threadIdx.x;   // 0..63
    float Rb = (b < BINS) ? red[b]        : 0.0f;
    float Cb = (b < BINS) ? red[BINS + b] : 0.0f;
    float RS = Rb, CS = Cb;
    for (int off = 1; off < 64; off <<= 1) { RS += __shfl_xor(RS, off); CS += __shfl_xor(CS, off); }
    float RA = red[60], CA = red[61];
    if (b == BINS - 1) { Rb = (RA - RS) + Rb; Cb = (CA - CS) + Cb; }
    float term = (b < BINS) ? (Rb - MU_F * Cb) / fmaxf(Cb, 1.0f) : 0.0f;
    float nz   = (b < BINS && Cb > 0.0f) ? 1.0f : 0.0f;
    for (int off = 1; off < 64; off <<= 1) { term += __shfl_xor(term, off); nz += __shfl_xor(nz, off); }
    if (b == 0) out[0] = term / fmaxf(nz, 1.0f);
}

// ---------------------------------------------------------------------------
extern "C" void kernel_launch(void* const* d_in, const int* in_sizes, int n_in,
                              void* d_out, int out_size, void* d_ws, size_t ws_size,
                              hipStream_t stream) {
    int n = in_sizes[0];

    int NB = NBLK;
    size_t need = (size_t)ROWS * (size_t)NB * sizeof(float) + ROWS * sizeof(float);
    bool ws_ok = need <= ws_size;
    if (!ws_ok) {
        NB = (int)((ws_size / sizeof(float) - ROWS) / ROWS);
        if (NB > NBLK) NB = NBLK;
        if (NB < 1) NB = 1;
    }
    int pstride = NB;
    float* part = (float*)d_ws;                  // [ROWS][pstride]
    float* red  = part + (size_t)ROWS * pstride; // [ROWS]

    bool fast = ws_ok && (n % 16 == 0) && n > 0;

    if (fast) {
        int nchunks = n / 16;
        ghmr_hist_chunk<<<NB, THREADS, 0, stream>>>(
            (const float4*)d_in[0], (const float4*)d_in[1], (const float4*)d_in[2],
            part, pstride, nchunks);
    } else {
        ghmr_hist_gen<<<NB, THREADS, 0, stream>>>(
            (const float*)d_in[0], (const float*)d_in[1], (const float*)d_in[2],
            part, pstride, n);
    }
    ghmr_reduce<<<ROWS, 256, 0, stream>>>(part, red, pstride, NB);
    ghmr_final<<<1, 64, 0, stream>>>(red, (float*)d_out);
}